// Round 2
// baseline (567.803 us; speedup 1.0000x reference)
//
#include <hip/hip_runtime.h>
#include <math.h>

// Problem constants
#define B_SZ 256
#define S_SZ 6
#define D_SZ 10000
#define DP   10112      // D padded to 158*64
#define C_SZ 128
#define K_SZ 500
#define KP   512        // codebook rows padded (8 k-tiles of 64)
#define NIT  (DP / 64)  // 158 K-iterations
#define THR  1.0f       // repair window; hi-only error bound <= ~0.30 per value
#define RCAP 32768      // repair list capacity = all rows (never overflows)

typedef _Float16     half8  __attribute__((ext_vector_type(8)));
typedef float        f32x4  __attribute__((ext_vector_type(4)));
typedef unsigned int u32x4v __attribute__((ext_vector_type(4)));

__device__ __forceinline__ void stage16(const void* g, void* l) {
    __builtin_amdgcn_global_load_lds(
        (const __attribute__((address_space(1))) unsigned int*)g,
        (__attribute__((address_space(3))) unsigned int*)l, 16, 0, 0);
}

// ---- prep: W_reg fp32 -> f16 hi only (lo path removed; near-ties repaired exactly) ----
__global__ void prep_whi(const float* __restrict__ wreg, _Float16* __restrict__ whi,
                         int* __restrict__ counter) {
    if (blockIdx.x == 0 && threadIdx.x == 0) *counter = 0;  // zero repair counter early
    int t = blockIdx.x * 256 + threadIdx.x;
    if (t >= C_SZ * DP) return;
    int c = t / DP, d = t - c * DP;
    float w = (d < D_SZ) ? wreg[c * D_SZ + d] : 0.0f;
    whi[t] = (_Float16)w;
}

// ---- prep: codebook (±1 fp32) -> f16, zero-padded to [512][DP] ----
__global__ void prep_cb(const float* __restrict__ cb, _Float16* __restrict__ cbp) {
    int t = blockIdx.x * 256 + threadIdx.x;
    if (t >= KP * DP) return;
    int k = t / DP, d = t - k * DP;
    float v = (k < K_SZ && d < D_SZ) ? cb[k * D_SZ + d] : 0.0f;
    cbp[t] = (_Float16)v;
}

// ---- prep: enc sign mask (0x0000 = +1, 0x8000 = -1), fp64 for exact sign match ----
__global__ void prep_enc(const float* __restrict__ x, const float* __restrict__ wp,
                         const float* __restrict__ bp, unsigned short* __restrict__ em) {
    int t = blockIdx.x * 256 + threadIdx.x;
    if (t >= B_SZ * DP) return;
    int b = t / DP, d = t - b * DP;
    unsigned short m = 0;
    if (d < D_SZ) {
        double p = 0.0;
        #pragma unroll
        for (int s = 0; s < S_SZ; ++s)
            p += (double)x[b * S_SZ + s] * (double)wp[d * S_SZ + s];
        double hv = cos(p + (double)bp[d]) * sin(p);
        m = (hv > 0.0) ? (unsigned short)0u : (unsigned short)0x8000u;
    }
    em[t] = m;
}

// ---- main: block = 8 batches x 64c x 64k; hi-only f16 MFMA; writes f16 sim tile.
// Staged A/B tiles are batch-independent, signs XORed onto B fragments
// (bit-exact: a*(s*b) = s*(a*b)). 8x LDS/staging reuse rebalances the
// LDS-read:MFMA pipe ratio after dropping the lo-MFMA (1.44 -> ~1.03).
// LDS XOR-swizzled: 16-B chunk p of row r holds logical chunk (p ^ (r&7)).
__global__ __launch_bounds__(256, 2) void gemm_sim(
    const _Float16* __restrict__ whi, const _Float16* __restrict__ cbp,
    const unsigned short* __restrict__ em, _Float16* __restrict__ simh)
{
    const int kt = blockIdx.x >> 1;   // 0..7  k-tile (64 codebook rows)
    const int ct = blockIdx.x & 1;    // 0..1  c-tile (64 classes)
    const int bg = blockIdx.y;        // 0..31 batch group (8 batches)
    const int tid  = threadIdx.x;
    const int wave = tid >> 6;
    const int lane = tid & 63;
    const int quad = lane >> 4;
    const int col  = lane & 15;
    const int ch32 = (wave & 1) * 32;   // c offset of this wave's 32x32-per-b
    const int kh32 = (wave >> 1) * 32;  // k offset

    __shared__ __align__(16) _Float16 s_whi[64 * 64];
    __shared__ __align__(16) _Float16 s_cb [64 * 64];
    __shared__ __align__(16) unsigned short s_mask[8 * 64];

    f32x4 acc[8][2][2];
    #pragma unroll
    for (int b = 0; b < 8; ++b)
        #pragma unroll
        for (int m = 0; m < 2; ++m)
            #pragma unroll
            for (int n = 0; n < 2; ++n)
                acc[b][m][n] = (f32x4){0.f, 0.f, 0.f, 0.f};

    const int c0  = ct * 64;
    const int kr0 = kt * 64;
    const int bg8 = bg * 8;

    // staging geometry: slot e: row=e>>3, pos p=e&7; global chunk = p^(row&7)
    size_t abase[2], bbase[2];
    int soff[2];
    #pragma unroll
    for (int s = 0; s < 2; ++s) {
        int e = s * 256 + tid;          // 0..511
        int row = e >> 3;
        int p = e & 7;
        int gcol = (p ^ (row & 7)) * 8;
        abase[s] = (size_t)(c0 + row) * DP + gcol;
        bbase[s] = (size_t)(kr0 + row) * DP + gcol;
        soff[s] = e * 8;
    }

    for (int kb = 0; kb < NIT; ++kb) {
        const int k0 = kb * 64;
        #pragma unroll
        for (int s = 0; s < 2; ++s) {
            stage16(whi + abase[s] + k0, s_whi + soff[s]);
            stage16(cbp + bbase[s] + k0, s_cb  + soff[s]);
        }
        if (tid < 64) {  // 8 b x 64 ushort masks = 1 KiB; lane-linear LDS dest
            stage16(em + (size_t)(bg8 + (tid >> 3)) * DP + k0 + (tid & 7) * 8,
                    s_mask + tid * 8);
        }
        __syncthreads();

        // preload both k2 phases' A/B fragments: phase-1 loads stay in flight
        // (lgkmcnt>0) while phase-0 MFMAs run.
        u32x4v ah[2][2], br[2][2];
        #pragma unroll
        for (int k2 = 0; k2 < 2; ++k2) {
            const int chunk = k2 * 4 + quad;
            const int sw    = (chunk ^ (col & 7)) * 8;
            #pragma unroll
            for (int m = 0; m < 2; ++m)
                ah[k2][m] = *(const u32x4v*)(s_whi + (ch32 + m * 16 + col) * 64 + sw);
            #pragma unroll
            for (int n = 0; n < 2; ++n)
                br[k2][n] = *(const u32x4v*)(s_cb + (kh32 + n * 16 + col) * 64 + sw);
        }
        #pragma unroll
        for (int k2 = 0; k2 < 2; ++k2) {
            const int koff = (k2 * 4 + quad) * 8;
            #pragma unroll
            for (int b = 0; b < 8; ++b) {
                const u32x4v mrb = *(const u32x4v*)(s_mask + b * 64 + koff);
                half8 bs0 = __builtin_bit_cast(half8, br[k2][0] ^ mrb);
                half8 bs1 = __builtin_bit_cast(half8, br[k2][1] ^ mrb);
                #pragma unroll
                for (int m = 0; m < 2; ++m) {
                    half8 a = __builtin_bit_cast(half8, ah[k2][m]);
                    acc[b][m][0] = __builtin_amdgcn_mfma_f32_16x16x32_f16(a, bs0, acc[b][m][0], 0, 0, 0);
                    acc[b][m][1] = __builtin_amdgcn_mfma_f32_16x16x32_f16(a, bs1, acc[b][m][1], 0, 0, 0);
                }
            }
        }
        __syncthreads();
    }

    // ---- epilogue: store f16 sim tile. C/D layout (16x16): col=lane&15 (k),
    // row = quad*4 + reg (c). 16 consecutive k per 16-lane group -> 32B segments.
    #pragma unroll
    for (int b = 0; b < 8; ++b) {
        const size_t base = ((size_t)(bg8 + b) * C_SZ + (size_t)(c0 + ch32)) * KP;
        #pragma unroll
        for (int m = 0; m < 2; ++m)
            #pragma unroll
            for (int n = 0; n < 2; ++n) {
                const int kg = kr0 + kh32 + n * 16 + col;
                #pragma unroll
                for (int r = 0; r < 4; ++r) {
                    const int cl = m * 16 + quad * 4 + r;
                    simh[base + (size_t)cl * KP + kg] = (_Float16)acc[b][m][n][r];
                }
            }
    }
}

// ---- pass 2: per (b,c) row of 512 f16 sims: top-2 over k<500; gap >= THR is
// provably safe (2 x 0.30 error bound < 1.0); else flag row for exact repair.
__global__ __launch_bounds__(256) void argmax_gap(
    const _Float16* __restrict__ simh, float* __restrict__ out,
    int* __restrict__ counter, int* __restrict__ list)
{
    const int wave = threadIdx.x >> 6, lane = threadIdx.x & 63;
    const int row = blockIdx.x * 4 + wave;       // 8192 blocks x 4 rows
    const half8 v = *(const half8*)(simh + (size_t)row * KP + lane * 8);
    float bv = -3.0e38f, bv2 = -3.0e38f; int bk = 0x7fffffff;
    #pragma unroll
    for (int j = 0; j < 8; ++j) {
        const int k = lane * 8 + j;
        const float f = (k < K_SZ) ? (float)v[j] : -3.0e38f;
        if (f > bv)       { bv2 = bv; bv = f; bk = k; }
        else if (f > bv2) { bv2 = f; }
    }
    #pragma unroll
    for (int off = 1; off < 64; off <<= 1) {
        const float ov  = __shfl_xor(bv,  off, 64);
        const int   ok  = __shfl_xor(bk,  off, 64);
        const float ov2 = __shfl_xor(bv2, off, 64);
        if (ov > bv || (ov == bv && ok < bk)) { bv2 = fmaxf(bv, ov2); bv = ov; bk = ok; }
        else                                  { bv2 = fmaxf(ov, bv2); }
    }
    if (lane == 0) {
        out[row] = (float)bk * (61.5f / 499.0f) - 19.9f;
        if (bv - bv2 < THR) {
            const int idx = atomicAdd(counter, 1);
            if (idx < RCAP) list[idx] = row;
        }
    }
}

// ---- pass 3: exact fp64 recompute of candidate k's (within THR of row max)
// for flagged rows only; lowest-k tie-break matches jnp.argmax.
__global__ __launch_bounds__(256) void repair(
    const _Float16* __restrict__ simh, const int* __restrict__ list,
    const int* __restrict__ counter, const unsigned short* __restrict__ em,
    const float* __restrict__ wreg, const float* __restrict__ cb,
    float* __restrict__ out)
{
    __shared__ float  srow[KP];
    __shared__ double sred[4];
    __shared__ float  smax[4];
    const int tid = threadIdx.x;
    int n = *counter;
    if (n > RCAP) n = RCAP;
    for (int i = blockIdx.x; i < n; i += gridDim.x) {
        const int row = list[i];
        const int b = row >> 7, c = row & 127;
        srow[tid]       = (float)simh[(size_t)row * KP + tid];
        srow[tid + 256] = (float)simh[(size_t)row * KP + tid + 256];
        __syncthreads();
        float m = -3.0e38f;
        for (int k = tid; k < K_SZ; k += 256) m = fmaxf(m, srow[k]);
        #pragma unroll
        for (int off = 32; off; off >>= 1) m = fmaxf(m, __shfl_down(m, off, 64));
        if ((tid & 63) == 0) smax[tid >> 6] = m;
        __syncthreads();
        const float thr = fmaxf(fmaxf(smax[0], smax[1]), fmaxf(smax[2], smax[3])) - THR;
        double best = -1.0e300; int bestk = 0;
        for (int k = 0; k < K_SZ; ++k) {
            if (srow[k] < thr) continue;            // uniform branch (LDS value)
            double s = 0.0;
            for (int d = tid; d < D_SZ; d += 256) {
                const double p = (double)wreg[c * D_SZ + d] * (double)cb[k * D_SZ + d];
                s += em[(size_t)b * DP + d] ? -p : p;
            }
            #pragma unroll
            for (int off = 32; off; off >>= 1) s += __shfl_down(s, off, 64);
            if ((tid & 63) == 0) sred[tid >> 6] = s;
            __syncthreads();
            if (tid == 0) {
                const double tot = sred[0] + sred[1] + sred[2] + sred[3];
                if (tot > best) { best = tot; bestk = k; }
            }
            __syncthreads();
        }
        if (tid == 0) out[row] = (float)bestk * (61.5f / 499.0f) - 19.9f;
        __syncthreads();
    }
}

extern "C" void kernel_launch(void* const* d_in, const int* in_sizes, int n_in,
                              void* d_out, int out_size, void* d_ws, size_t ws_size,
                              hipStream_t stream) {
    const float* x    = (const float*)d_in[0];
    const float* wp   = (const float*)d_in[1];
    const float* bp   = (const float*)d_in[2];
    const float* wreg = (const float*)d_in[3];
    const float* cb   = (const float*)d_in[4];
    float* out = (float*)d_out;

    char* ws = (char*)d_ws;
    size_t o = 0;
    auto take = [&](size_t bytes) -> char* {
        o = (o + 255) & ~(size_t)255;
        char* p = ws + o;
        o += bytes;
        return p;
    };
    _Float16* whi       = (_Float16*)take(sizeof(_Float16) * C_SZ * DP);
    _Float16* cbp       = (_Float16*)take(sizeof(_Float16) * KP * DP);
    unsigned short* em  = (unsigned short*)take(sizeof(unsigned short) * B_SZ * DP);
    _Float16* simh      = (_Float16*)take(sizeof(_Float16) * (size_t)B_SZ * C_SZ * KP);
    int* counter        = (int*)take(sizeof(int));
    int* list           = (int*)take(sizeof(int) * RCAP);
    (void)ws_size; (void)in_sizes; (void)n_in; (void)out_size;

    prep_whi<<<(C_SZ * DP + 255) / 256, 256, 0, stream>>>(wreg, whi, counter);
    prep_cb<<<(KP * DP + 255) / 256, 256, 0, stream>>>(cb, cbp);
    prep_enc<<<(B_SZ * DP + 255) / 256, 256, 0, stream>>>(x, wp, bp, em);

    dim3 g(16, 32);  // x: kt*2+ct, y: batch group of 8 -> 512 blocks = 2/CU exactly
    gemm_sim<<<g, 256, 0, stream>>>(whi, cbp, em, simh);

    // 8192 blocks x 4 rows = 32768 (b,c) rows  [R1 fix: was /64 too few blocks]
    argmax_gap<<<(B_SZ * C_SZ) / 4, 256, 0, stream>>>(simh, out, counter, list);
    repair<<<256, 256, 0, stream>>>(simh, list, counter, em, wreg, cb, out);
}

// Round 3
// 559.507 us; speedup vs baseline: 1.0148x; 1.0148x over previous
//
#include <hip/hip_runtime.h>
#include <math.h>

// Problem constants
#define B_SZ 256
#define S_SZ 6
#define D_SZ 10000
#define DP   10112      // D padded to 158*64
#define C_SZ 128
#define K_SZ 500
#define KP   512        // codebook rows padded (8 k-tiles of 64)
#define NIT  (DP / 64)  // 158 K-iterations
#define THR  1.0f       // repair window; hi-only error bound <= ~0.30 per value
#define RCAP 32768      // repair list capacity = all rows (never overflows)

typedef _Float16     half8  __attribute__((ext_vector_type(8)));
typedef float        f32x4  __attribute__((ext_vector_type(4)));
typedef unsigned int u32x4v __attribute__((ext_vector_type(4)));

__device__ __forceinline__ void stage16(const void* g, void* l) {
    __builtin_amdgcn_global_load_lds(
        (const __attribute__((address_space(1))) unsigned int*)g,
        (__attribute__((address_space(3))) unsigned int*)l, 16, 0, 0);
}

// ---- prep: W_reg fp32 -> f16 hi only (lo path removed; near-ties repaired exactly) ----
__global__ void prep_whi(const float* __restrict__ wreg, _Float16* __restrict__ whi,
                         int* __restrict__ counter) {
    if (blockIdx.x == 0 && threadIdx.x == 0) *counter = 0;  // zero repair counter early
    int t = blockIdx.x * 256 + threadIdx.x;
    if (t >= C_SZ * DP) return;
    int c = t / DP, d = t - c * DP;
    float w = (d < D_SZ) ? wreg[c * D_SZ + d] : 0.0f;
    whi[t] = (_Float16)w;
}

// ---- prep: codebook (±1 fp32) -> f16, zero-padded to [512][DP] ----
__global__ void prep_cb(const float* __restrict__ cb, _Float16* __restrict__ cbp) {
    int t = blockIdx.x * 256 + threadIdx.x;
    if (t >= KP * DP) return;
    int k = t / DP, d = t - k * DP;
    float v = (k < K_SZ && d < D_SZ) ? cb[k * D_SZ + d] : 0.0f;
    cbp[t] = (_Float16)v;
}

// ---- prep: enc sign mask (0x0000 = +1, 0x8000 = -1).
// Sign-only: never evaluate cos/sin. In fp64:
//   sign(sin t)  = + iff frac(t/2pi) in (0, 0.5)
//   sign(cos t)  = + iff frac(t/2pi) < 0.25 or > 0.75
// hv = cos(p+b)*sin(p) > 0 iff the two predicates agree. Same fp64-true
// sign semantics as the old fp64 sincos (boundaries are measure-zero),
// ~20x fewer instructions (kills the ~245 us fp64-transcendental cost).
__global__ void prep_enc(const float* __restrict__ x, const float* __restrict__ wp,
                         const float* __restrict__ bp, unsigned short* __restrict__ em) {
    int t = blockIdx.x * 256 + threadIdx.x;
    if (t >= B_SZ * DP) return;
    int b = t / DP, d = t - b * DP;
    unsigned short m = 0;
    if (d < D_SZ) {
        double p = 0.0;
        #pragma unroll
        for (int s = 0; s < S_SZ; ++s)
            p += (double)x[b * S_SZ + s] * (double)wp[d * S_SZ + s];
        const double inv2pi = 0.15915494309189535;
        double t1 = p * inv2pi;
        double f1 = t1 - floor(t1);                     // sin(p) sign
        double t2 = (p + (double)bp[d]) * inv2pi;
        double f2 = t2 - floor(t2);                     // cos(p+b) sign
        bool sin_pos = (f1 < 0.5);
        bool cos_pos = (f2 < 0.25) || (f2 > 0.75);
        m = (sin_pos == cos_pos) ? (unsigned short)0u : (unsigned short)0x8000u;
    }
    em[t] = m;
}

// ---- main: block = 8 batches x 64c x 64k; hi-only f16 MFMA; writes f16 sim tile.
// Wave decomposition (R2): each of the 4 waves owns 2 BATCHES x the full
// 64x64 (c,k) tile (was: 4 waves splitting (c,k), each doing all 8 batches).
// Per (k2,b) the 4 signed-B fragments are reused across all 4 m:
// XOR count 128 -> 64 per thread/iter, mask ds_reads 16 -> 4.
// Signs XORed onto B fragments (bit-exact: a*(s*b) = s*(a*b)).
// LDS XOR-swizzled: 16-B chunk p of row r holds logical chunk (p ^ (r&7)).
__global__ __launch_bounds__(256, 2) void gemm_sim(
    const _Float16* __restrict__ whi, const _Float16* __restrict__ cbp,
    const unsigned short* __restrict__ em, _Float16* __restrict__ simh)
{
    const int kt = blockIdx.x >> 1;   // 0..7  k-tile (64 codebook rows)
    const int ct = blockIdx.x & 1;    // 0..1  c-tile (64 classes)
    const int bg = blockIdx.y;        // 0..31 batch group (8 batches)
    const int tid  = threadIdx.x;
    const int wave = tid >> 6;        // owns batches {2*wave, 2*wave+1}
    const int lane = tid & 63;
    const int quad = lane >> 4;
    const int col  = lane & 15;

    __shared__ __align__(16) _Float16 s_whi[64 * 64];
    __shared__ __align__(16) _Float16 s_cb [64 * 64];
    __shared__ __align__(16) unsigned short s_mask[8 * 64];

    f32x4 acc[2][4][4];
    #pragma unroll
    for (int b = 0; b < 2; ++b)
        #pragma unroll
        for (int m = 0; m < 4; ++m)
            #pragma unroll
            for (int n = 0; n < 4; ++n)
                acc[b][m][n] = (f32x4){0.f, 0.f, 0.f, 0.f};

    const int c0  = ct * 64;
    const int kr0 = kt * 64;
    const int bg8 = bg * 8;

    // staging geometry: slot e: row=e>>3, pos p=e&7; global chunk = p^(row&7)
    size_t abase[2], bbase[2];
    int soff[2];
    #pragma unroll
    for (int s = 0; s < 2; ++s) {
        int e = s * 256 + tid;          // 0..511
        int row = e >> 3;
        int p = e & 7;
        int gcol = (p ^ (row & 7)) * 8;
        abase[s] = (size_t)(c0 + row) * DP + gcol;
        bbase[s] = (size_t)(kr0 + row) * DP + gcol;
        soff[s] = e * 8;
    }

    for (int kb = 0; kb < NIT; ++kb) {
        const int k0 = kb * 64;
        #pragma unroll
        for (int s = 0; s < 2; ++s) {
            stage16(whi + abase[s] + k0, s_whi + soff[s]);
            stage16(cbp + bbase[s] + k0, s_cb  + soff[s]);
        }
        if (tid < 64) {  // 8 b x 64 ushort masks = 1 KiB; lane-linear LDS dest
            stage16(em + (size_t)(bg8 + (tid >> 3)) * DP + k0 + (tid & 7) * 8,
                    s_mask + tid * 8);
        }
        __syncthreads();

        // preload both k2 phases' fragments: later loads stay in flight
        // (lgkmcnt>0) while earlier MFMAs run.
        u32x4v ah[2][4], br[2][4], mr[2][2];
        #pragma unroll
        for (int k2 = 0; k2 < 2; ++k2) {
            const int chunk = k2 * 4 + quad;
            const int sw    = (chunk ^ (col & 7)) * 8;
            #pragma unroll
            for (int m = 0; m < 4; ++m)
                ah[k2][m] = *(const u32x4v*)(s_whi + (m * 16 + col) * 64 + sw);
            #pragma unroll
            for (int n = 0; n < 4; ++n)
                br[k2][n] = *(const u32x4v*)(s_cb + (n * 16 + col) * 64 + sw);
            #pragma unroll
            for (int b = 0; b < 2; ++b)
                mr[k2][b] = *(const u32x4v*)(s_mask + (wave * 2 + b) * 64 + chunk * 8);
        }
        #pragma unroll
        for (int k2 = 0; k2 < 2; ++k2) {
            #pragma unroll
            for (int b = 0; b < 2; ++b) {
                half8 bs[4];
                #pragma unroll
                for (int n = 0; n < 4; ++n)
                    bs[n] = __builtin_bit_cast(half8, br[k2][n] ^ mr[k2][b]);
                #pragma unroll
                for (int m = 0; m < 4; ++m) {
                    half8 a = __builtin_bit_cast(half8, ah[k2][m]);
                    #pragma unroll
                    for (int n = 0; n < 4; ++n)
                        acc[b][m][n] = __builtin_amdgcn_mfma_f32_16x16x32_f16(a, bs[n], acc[b][m][n], 0, 0, 0);
                }
            }
        }
        __syncthreads();
    }

    // ---- epilogue: store f16 sim tile. C/D layout (16x16): col=lane&15 (k),
    // row = quad*4 + reg (c). Each wave stores its 2 batches' full 64x64 tile.
    #pragma unroll
    for (int b = 0; b < 2; ++b) {
        const size_t base = ((size_t)(bg8 + wave * 2 + b) * C_SZ + (size_t)c0) * KP;
        #pragma unroll
        for (int m = 0; m < 4; ++m)
            #pragma unroll
            for (int n = 0; n < 4; ++n) {
                const int kg = kr0 + n * 16 + col;
                #pragma unroll
                for (int r = 0; r < 4; ++r) {
                    const int cl = m * 16 + quad * 4 + r;
                    simh[base + (size_t)cl * KP + kg] = (_Float16)acc[b][m][n][r];
                }
            }
    }
}

// ---- pass 2: per (b,c) row of 512 f16 sims: top-2 over k<500; gap >= THR is
// provably safe (2 x 0.30 error bound < 1.0); else flag row for exact repair.
__global__ __launch_bounds__(256) void argmax_gap(
    const _Float16* __restrict__ simh, float* __restrict__ out,
    int* __restrict__ counter, int* __restrict__ list)
{
    const int wave = threadIdx.x >> 6, lane = threadIdx.x & 63;
    const int row = blockIdx.x * 4 + wave;       // 8192 blocks x 4 rows
    const half8 v = *(const half8*)(simh + (size_t)row * KP + lane * 8);
    float bv = -3.0e38f, bv2 = -3.0e38f; int bk = 0x7fffffff;
    #pragma unroll
    for (int j = 0; j < 8; ++j) {
        const int k = lane * 8 + j;
        const float f = (k < K_SZ) ? (float)v[j] : -3.0e38f;
        if (f > bv)       { bv2 = bv; bv = f; bk = k; }
        else if (f > bv2) { bv2 = f; }
    }
    #pragma unroll
    for (int off = 1; off < 64; off <<= 1) {
        const float ov  = __shfl_xor(bv,  off, 64);
        const int   ok  = __shfl_xor(bk,  off, 64);
        const float ov2 = __shfl_xor(bv2, off, 64);
        if (ov > bv || (ov == bv && ok < bk)) { bv2 = fmaxf(bv, ov2); bv = ov; bk = ok; }
        else                                  { bv2 = fmaxf(ov, bv2); }
    }
    if (lane == 0) {
        out[row] = (float)bk * (61.5f / 499.0f) - 19.9f;
        if (bv - bv2 < THR) {
            const int idx = atomicAdd(counter, 1);
            if (idx < RCAP) list[idx] = row;
        }
    }
}

// ---- pass 3: exact fp64 recompute of candidate k's (within THR of row max)
// for flagged rows only; lowest-k tie-break matches jnp.argmax.
__global__ __launch_bounds__(256) void repair(
    const _Float16* __restrict__ simh, const int* __restrict__ list,
    const int* __restrict__ counter, const unsigned short* __restrict__ em,
    const float* __restrict__ wreg, const float* __restrict__ cb,
    float* __restrict__ out)
{
    __shared__ float  srow[KP];
    __shared__ double sred[4];
    __shared__ float  smax[4];
    const int tid = threadIdx.x;
    int n = *counter;
    if (n > RCAP) n = RCAP;
    for (int i = blockIdx.x; i < n; i += gridDim.x) {
        const int row = list[i];
        const int b = row >> 7, c = row & 127;
        srow[tid]       = (float)simh[(size_t)row * KP + tid];
        srow[tid + 256] = (float)simh[(size_t)row * KP + tid + 256];
        __syncthreads();
        float m = -3.0e38f;
        for (int k = tid; k < K_SZ; k += 256) m = fmaxf(m, srow[k]);
        #pragma unroll
        for (int off = 32; off; off >>= 1) m = fmaxf(m, __shfl_down(m, off, 64));
        if ((tid & 63) == 0) smax[tid >> 6] = m;
        __syncthreads();
        const float thr = fmaxf(fmaxf(smax[0], smax[1]), fmaxf(smax[2], smax[3])) - THR;
        double best = -1.0e300; int bestk = 0;
        for (int k = 0; k < K_SZ; ++k) {
            if (srow[k] < thr) continue;            // uniform branch (LDS value)
            double s = 0.0;
            for (int d = tid; d < D_SZ; d += 256) {
                const double p = (double)wreg[c * D_SZ + d] * (double)cb[k * D_SZ + d];
                s += em[(size_t)b * DP + d] ? -p : p;
            }
            #pragma unroll
            for (int off = 32; off; off >>= 1) s += __shfl_down(s, off, 64);
            if ((tid & 63) == 0) sred[tid >> 6] = s;
            __syncthreads();
            if (tid == 0) {
                const double tot = sred[0] + sred[1] + sred[2] + sred[3];
                if (tot > best) { best = tot; bestk = k; }
            }
            __syncthreads();
        }
        if (tid == 0) out[row] = (float)bestk * (61.5f / 499.0f) - 19.9f;
        __syncthreads();
    }
}

extern "C" void kernel_launch(void* const* d_in, const int* in_sizes, int n_in,
                              void* d_out, int out_size, void* d_ws, size_t ws_size,
                              hipStream_t stream) {
    const float* x    = (const float*)d_in[0];
    const float* wp   = (const float*)d_in[1];
    const float* bp   = (const float*)d_in[2];
    const float* wreg = (const float*)d_in[3];
    const float* cb   = (const float*)d_in[4];
    float* out = (float*)d_out;

    char* ws = (char*)d_ws;
    size_t o = 0;
    auto take = [&](size_t bytes) -> char* {
        o = (o + 255) & ~(size_t)255;
        char* p = ws + o;
        o += bytes;
        return p;
    };
    _Float16* whi       = (_Float16*)take(sizeof(_Float16) * C_SZ * DP);
    _Float16* cbp       = (_Float16*)take(sizeof(_Float16) * KP * DP);
    unsigned short* em  = (unsigned short*)take(sizeof(unsigned short) * B_SZ * DP);
    _Float16* simh      = (_Float16*)take(sizeof(_Float16) * (size_t)B_SZ * C_SZ * KP);
    int* counter        = (int*)take(sizeof(int));
    int* list           = (int*)take(sizeof(int) * RCAP);
    (void)ws_size; (void)in_sizes; (void)n_in; (void)out_size;

    prep_whi<<<(C_SZ * DP + 255) / 256, 256, 0, stream>>>(wreg, whi, counter);
    prep_cb<<<(KP * DP + 255) / 256, 256, 0, stream>>>(cb, cbp);
    prep_enc<<<(B_SZ * DP + 255) / 256, 256, 0, stream>>>(x, wp, bp, em);

    dim3 g(16, 32);  // x: kt*2+ct, y: batch group of 8 -> 512 blocks = 2/CU exactly
    gemm_sim<<<g, 256, 0, stream>>>(whi, cbp, em, simh);

    // 8192 blocks x 4 rows = 32768 (b,c) rows
    argmax_gap<<<(B_SZ * C_SZ) / 4, 256, 0, stream>>>(simh, out, counter, list);
    repair<<<256, 256, 0, stream>>>(simh, list, counter, em, wreg, cb, out);
}

// Round 4
// 462.324 us; speedup vs baseline: 1.2281x; 1.2102x over previous
//
#include <hip/hip_runtime.h>
#include <math.h>

// Problem constants
#define B_SZ 256
#define S_SZ 6
#define D_SZ 10000
#define DP   10112      // D padded to 158*64
#define C_SZ 128
#define K_SZ 500
#define KP   512        // codebook rows padded (8 k-tiles of 64)
#define NIT  (DP / 64)  // 158 K-iterations
#define THR  1.0f       // repair window; hi-only error bound <= ~0.29/value, 0.58/gap
#define RCAP 32768      // repair list capacity = all rows (never overflows)

typedef _Float16     half8  __attribute__((ext_vector_type(8)));
typedef float        f32x4  __attribute__((ext_vector_type(4)));
typedef unsigned int u32x4v __attribute__((ext_vector_type(4)));

__device__ __forceinline__ void stage16(const void* g, void* l) {
    __builtin_amdgcn_global_load_lds(
        (const __attribute__((address_space(1))) unsigned int*)g,
        (__attribute__((address_space(3))) unsigned int*)l, 16, 0, 0);
}

// ---- prep: W_reg fp32 -> f16 hi only (near-ties repaired exactly in pass 3) ----
__global__ void prep_whi(const float* __restrict__ wreg, _Float16* __restrict__ whi,
                         int* __restrict__ counter) {
    if (blockIdx.x == 0 && threadIdx.x == 0) *counter = 0;  // zero repair counter early
    int t = blockIdx.x * 256 + threadIdx.x;
    if (t >= C_SZ * DP) return;
    int c = t / DP, d = t - c * DP;
    float w = (d < D_SZ) ? wreg[c * D_SZ + d] : 0.0f;
    whi[t] = (_Float16)w;
}

// ---- prep: codebook (±1 fp32) -> f16, zero-padded to [512][DP] ----
__global__ void prep_cb(const float* __restrict__ cb, _Float16* __restrict__ cbp) {
    int t = blockIdx.x * 256 + threadIdx.x;
    if (t >= KP * DP) return;
    int k = t / DP, d = t - k * DP;
    float v = (k < K_SZ && d < D_SZ) ? cb[k * D_SZ + d] : 0.0f;
    cbp[t] = (_Float16)v;
}

// ---- prep: enc sign mask (0x0000 = +1, 0x8000 = -1).
// Sign-only: sign(sin t) = + iff frac(t/2pi) < 0.5;
//            sign(cos t) = + iff frac(t/2pi) < 0.25 or > 0.75.
// Product > 0 iff predicates agree. fp64-true signs (boundaries measure-zero).
__global__ void prep_enc(const float* __restrict__ x, const float* __restrict__ wp,
                         const float* __restrict__ bp, unsigned short* __restrict__ em) {
    int t = blockIdx.x * 256 + threadIdx.x;
    if (t >= B_SZ * DP) return;
    int b = t / DP, d = t - b * DP;
    unsigned short m = 0;
    if (d < D_SZ) {
        double p = 0.0;
        #pragma unroll
        for (int s = 0; s < S_SZ; ++s)
            p += (double)x[b * S_SZ + s] * (double)wp[d * S_SZ + s];
        const double inv2pi = 0.15915494309189535;
        double t1 = p * inv2pi;
        double f1 = t1 - floor(t1);                     // sin(p) sign
        double t2 = (p + (double)bp[d]) * inv2pi;
        double f2 = t2 - floor(t2);                     // cos(p+b) sign
        bool sin_pos = (f1 < 0.5);
        bool cos_pos = (f2 < 0.25) || (f2 > 0.75);
        m = (sin_pos == cos_pos) ? (unsigned short)0u : (unsigned short)0x8000u;
    }
    em[t] = m;
}

// ---- main: block = 8 batches x 64c x 64k; hi-only f16 MFMA; writes f16 sim tile.
// Each of the 4 waves owns 2 BATCHES x the full 64x64 (c,k) tile.
// Signs XORed onto B fragments (bit-exact: a*(s*b) = s*(a*b)).
// LDS XOR-swizzled: 16-B chunk p of row r holds logical chunk (p ^ (r&7)).
// R4: double-buffered staging — tile t+1's global_load_lds issued BEFORE tile
// t's MFMAs; the vmcnt(0) drain at the end-of-iter barrier finds loads landed
// (was: issue->drain back-to-back, ~1700 cyc/iter exposed latency at 2 waves/SIMD).
__global__ __launch_bounds__(256, 2) void gemm_sim(
    const _Float16* __restrict__ whi, const _Float16* __restrict__ cbp,
    const unsigned short* __restrict__ em, _Float16* __restrict__ simh)
{
    const int kt = blockIdx.x >> 1;   // 0..7  k-tile (64 codebook rows)
    const int ct = blockIdx.x & 1;    // 0..1  c-tile (64 classes)
    const int bg = blockIdx.y;        // 0..31 batch group (8 batches)
    const int tid  = threadIdx.x;
    const int wave = tid >> 6;        // owns batches {2*wave, 2*wave+1}
    const int lane = tid & 63;
    const int quad = lane >> 4;
    const int col  = lane & 15;

    __shared__ __align__(16) _Float16 s_whi[2][64 * 64];
    __shared__ __align__(16) _Float16 s_cb [2][64 * 64];
    __shared__ __align__(16) unsigned short s_mask[2][8 * 64];

    f32x4 acc[2][4][4];
    #pragma unroll
    for (int b = 0; b < 2; ++b)
        #pragma unroll
        for (int m = 0; m < 4; ++m)
            #pragma unroll
            for (int n = 0; n < 4; ++n)
                acc[b][m][n] = (f32x4){0.f, 0.f, 0.f, 0.f};

    const int c0  = ct * 64;
    const int kr0 = kt * 64;
    const int bg8 = bg * 8;

    // staging geometry: slot e: row=e>>3, pos p=e&7; global chunk = p^(row&7)
    size_t abase[2], bbase[2];
    int soff[2];
    #pragma unroll
    for (int s = 0; s < 2; ++s) {
        int e = s * 256 + tid;          // 0..511
        int row = e >> 3;
        int p = e & 7;
        int gcol = (p ^ (row & 7)) * 8;
        abase[s] = (size_t)(c0 + row) * DP + gcol;
        bbase[s] = (size_t)(kr0 + row) * DP + gcol;
        soff[s] = e * 8;
    }
    const size_t embase = (size_t)(bg8 + (tid >> 3)) * DP + (tid & 7) * 8;

    auto STAGE = [&](int buf, int kb) {
        const int k0 = kb * 64;
        #pragma unroll
        for (int s = 0; s < 2; ++s) {
            stage16(whi + abase[s] + k0, &s_whi[buf][soff[s]]);
            stage16(cbp + bbase[s] + k0, &s_cb [buf][soff[s]]);
        }
        if (tid < 64)  // 8 b x 64 ushort masks = 1 KiB; lane-linear LDS dest
            stage16(em + embase + k0, &s_mask[buf][tid * 8]);
    };

    STAGE(0, 0);
    __syncthreads();   // compiler emits vmcnt(0) drain: tile 0 resident
    int cur = 0;

    for (int kb = 0; kb < NIT; ++kb) {
        if (kb + 1 < NIT) STAGE(cur ^ 1, kb + 1);   // next tile in flight under MFMAs

        // preload both k2 phases' fragments: later loads stay in flight
        // (lgkmcnt>0) while earlier MFMAs run.
        u32x4v ah[2][4], br[2][4], mr[2][2];
        #pragma unroll
        for (int k2 = 0; k2 < 2; ++k2) {
            const int chunk = k2 * 4 + quad;
            const int sw    = (chunk ^ (col & 7)) * 8;
            #pragma unroll
            for (int m = 0; m < 4; ++m)
                ah[k2][m] = *(const u32x4v*)(&s_whi[cur][(m * 16 + col) * 64 + sw]);
            #pragma unroll
            for (int n = 0; n < 4; ++n)
                br[k2][n] = *(const u32x4v*)(&s_cb[cur][(n * 16 + col) * 64 + sw]);
            #pragma unroll
            for (int b = 0; b < 2; ++b)
                mr[k2][b] = *(const u32x4v*)(&s_mask[cur][(wave * 2 + b) * 64 + chunk * 8]);
        }
        #pragma unroll
        for (int k2 = 0; k2 < 2; ++k2) {
            #pragma unroll
            for (int b = 0; b < 2; ++b) {
                half8 bs[4];
                #pragma unroll
                for (int n = 0; n < 4; ++n)
                    bs[n] = __builtin_bit_cast(half8, br[k2][n] ^ mr[k2][b]);
                #pragma unroll
                for (int m = 0; m < 4; ++m) {
                    half8 a = __builtin_bit_cast(half8, ah[k2][m]);
                    #pragma unroll
                    for (int n = 0; n < 4; ++n)
                        acc[b][m][n] = __builtin_amdgcn_mfma_f32_16x16x32_f16(a, bs[n], acc[b][m][n], 0, 0, 0);
                }
            }
        }
        __syncthreads();   // vmcnt(0)+lgkmcnt(0) drain: next tile ready, reads done
        cur ^= 1;
    }

    // ---- epilogue: store f16 sim tile. C/D layout (16x16): col=lane&15 (k),
    // row = quad*4 + reg (c). Each wave stores its 2 batches' full 64x64 tile.
    #pragma unroll
    for (int b = 0; b < 2; ++b) {
        const size_t base = ((size_t)(bg8 + wave * 2 + b) * C_SZ + (size_t)c0) * KP;
        #pragma unroll
        for (int m = 0; m < 4; ++m)
            #pragma unroll
            for (int n = 0; n < 4; ++n) {
                const int kg = kr0 + n * 16 + col;
                #pragma unroll
                for (int r = 0; r < 4; ++r) {
                    const int cl = m * 16 + quad * 4 + r;
                    simh[base + (size_t)cl * KP + kg] = (_Float16)acc[b][m][n][r];
                }
            }
    }
}

// ---- pass 2: per (b,c) row of 512 f16 sims: top-2 over k<500; gap >= THR is
// provably safe (2 x 0.29 error bound < 1.0); else flag row for exact repair.
__global__ __launch_bounds__(256) void argmax_gap(
    const _Float16* __restrict__ simh, float* __restrict__ out,
    int* __restrict__ counter, int* __restrict__ list)
{
    const int wave = threadIdx.x >> 6, lane = threadIdx.x & 63;
    const int row = blockIdx.x * 4 + wave;       // 8192 blocks x 4 rows
    const half8 v = *(const half8*)(simh + (size_t)row * KP + lane * 8);
    float bv = -3.0e38f, bv2 = -3.0e38f; int bk = 0x7fffffff;
    #pragma unroll
    for (int j = 0; j < 8; ++j) {
        const int k = lane * 8 + j;
        const float f = (k < K_SZ) ? (float)v[j] : -3.0e38f;
        if (f > bv)       { bv2 = bv; bv = f; bk = k; }
        else if (f > bv2) { bv2 = f; }
    }
    #pragma unroll
    for (int off = 1; off < 64; off <<= 1) {
        const float ov  = __shfl_xor(bv,  off, 64);
        const int   ok  = __shfl_xor(bk,  off, 64);
        const float ov2 = __shfl_xor(bv2, off, 64);
        if (ov > bv || (ov == bv && ok < bk)) { bv2 = fmaxf(bv, ov2); bv = ov; bk = ok; }
        else                                  { bv2 = fmaxf(ov, bv2); }
    }
    if (lane == 0) {
        out[row] = (float)bk * (61.5f / 499.0f) - 19.9f;
        if (bv - bv2 < THR) {
            const int idx = atomicAdd(counter, 1);
            if (idx < RCAP) list[idx] = row;
        }
    }
}

// ---- pass 3 (R4 rewrite): WAVE per flagged row. Row max + candidate set found
// fully in parallel (ballot + bit-scan, ~2-3 candidates/row); each candidate
// gets a cooperative 64-lane exact fp64 dot. Replaces the old serial 500-iter
// uniform-LDS scan (~27 us/row latency-bound -> ~2 us/row).
__global__ __launch_bounds__(256) void repair(
    const _Float16* __restrict__ simh, const int* __restrict__ list,
    const int* __restrict__ counter, const unsigned short* __restrict__ em,
    const float* __restrict__ wreg, const float* __restrict__ cb,
    float* __restrict__ out)
{
    const int wave = threadIdx.x >> 6, lane = threadIdx.x & 63;
    const int wid = blockIdx.x * 4 + wave;
    const int nw  = gridDim.x * 4;
    int n = *counter;
    if (n > RCAP) n = RCAP;
    for (int i = wid; i < n; i += nw) {
        const int row = list[i];
        const int b = row >> 7, c = row & 127;
        const half8 v = *(const half8*)(simh + (size_t)row * KP + lane * 8);
        float vf[8];
        float mx = -3.0e38f;
        #pragma unroll
        for (int j = 0; j < 8; ++j) {
            const int k = lane * 8 + j;
            vf[j] = (k < K_SZ) ? (float)v[j] : -3.0e38f;
            mx = fmaxf(mx, vf[j]);
        }
        #pragma unroll
        for (int off = 1; off < 64; off <<= 1)
            mx = fmaxf(mx, __shfl_xor(mx, off, 64));
        const float thr = mx - THR;   // true argmax provably within THR of stored max

        double best = -1.0e300; int bestk = 0x7fffffff;
        #pragma unroll
        for (int j = 0; j < 8; ++j) {
            unsigned long long bal = __ballot(vf[j] >= thr);
            while (bal) {
                const int l = __ffsll((long long)bal) - 1;
                bal &= bal - 1;
                const int k = l * 8 + j;          // candidate codebook row
                double s = 0.0;
                for (int d = lane; d < D_SZ; d += 64) {
                    const double p = (double)wreg[c * D_SZ + d] * (double)cb[k * D_SZ + d];
                    s += em[(size_t)b * DP + d] ? -p : p;
                }
                #pragma unroll
                for (int off = 1; off < 64; off <<= 1)
                    s += __shfl_xor(s, off, 64);
                if (s > best || (s == best && k < bestk)) { best = s; bestk = k; }
            }
        }
        if (lane == 0)
            out[row] = (float)bestk * (61.5f / 499.0f) - 19.9f;
    }
}

extern "C" void kernel_launch(void* const* d_in, const int* in_sizes, int n_in,
                              void* d_out, int out_size, void* d_ws, size_t ws_size,
                              hipStream_t stream) {
    const float* x    = (const float*)d_in[0];
    const float* wp   = (const float*)d_in[1];
    const float* bp   = (const float*)d_in[2];
    const float* wreg = (const float*)d_in[3];
    const float* cb   = (const float*)d_in[4];
    float* out = (float*)d_out;

    char* ws = (char*)d_ws;
    size_t o = 0;
    auto take = [&](size_t bytes) -> char* {
        o = (o + 255) & ~(size_t)255;
        char* p = ws + o;
        o += bytes;
        return p;
    };
    _Float16* whi       = (_Float16*)take(sizeof(_Float16) * C_SZ * DP);
    _Float16* cbp       = (_Float16*)take(sizeof(_Float16) * KP * DP);
    unsigned short* em  = (unsigned short*)take(sizeof(unsigned short) * B_SZ * DP);
    _Float16* simh      = (_Float16*)take(sizeof(_Float16) * (size_t)B_SZ * C_SZ * KP);
    int* counter        = (int*)take(sizeof(int));
    int* list           = (int*)take(sizeof(int) * RCAP);
    (void)ws_size; (void)in_sizes; (void)n_in; (void)out_size;

    prep_whi<<<(C_SZ * DP + 255) / 256, 256, 0, stream>>>(wreg, whi, counter);
    prep_cb<<<(KP * DP + 255) / 256, 256, 0, stream>>>(cb, cbp);
    prep_enc<<<(B_SZ * DP + 255) / 256, 256, 0, stream>>>(x, wp, bp, em);

    dim3 g(16, 32);  // x: kt*2+ct, y: batch group of 8 -> 512 blocks = 2/CU exactly
    gemm_sim<<<g, 256, 0, stream>>>(whi, cbp, em, simh);

    // 8192 blocks x 4 rows = 32768 (b,c) rows
    argmax_gap<<<(B_SZ * C_SZ) / 4, 256, 0, stream>>>(simh, out, counter, list);
    repair<<<256, 256, 0, stream>>>(simh, list, counter, em, wreg, cb, out);
}

// Round 5
// 413.973 us; speedup vs baseline: 1.3716x; 1.1168x over previous
//
#include <hip/hip_runtime.h>
#include <math.h>

// Problem constants
#define B_SZ 256
#define S_SZ 6
#define D_SZ 10000
#define DP   10112      // D padded to 158*64
#define C_SZ 128
#define K_SZ 500
#define KP   512        // codebook rows padded (8 k-tiles of 64)
#define NIT  (DP / 64)  // 158 K-iterations (even -> unroll-2 clean)
#define THR  1.0f       // repair window; hi-only error bound <= ~0.29/value, 0.58/gap
#define RCAP 32768      // repair list capacity = all rows (never overflows)

typedef _Float16       half8 __attribute__((ext_vector_type(8)));
typedef float          f32x4 __attribute__((ext_vector_type(4)));
typedef unsigned int   u32x4v __attribute__((ext_vector_type(4)));
typedef unsigned short u16x4 __attribute__((ext_vector_type(4)));
typedef unsigned int   u32x4b __attribute__((ext_vector_type(4)));

__device__ __forceinline__ void stage16(const void* g, void* l) {
    __builtin_amdgcn_global_load_lds(
        (const __attribute__((address_space(1))) unsigned int*)g,
        (__attribute__((address_space(3))) unsigned int*)l, 16, 0, 0);
}

// ---- prep: W_reg fp32 -> f16 hi only (near-ties repaired exactly in pass 3) ----
__global__ void prep_whi(const float* __restrict__ wreg, _Float16* __restrict__ whi,
                         int* __restrict__ counter) {
    if (blockIdx.x == 0 && threadIdx.x == 0) *counter = 0;  // zero repair counter early
    int t = blockIdx.x * 256 + threadIdx.x;
    if (t >= C_SZ * DP) return;
    int c = t / DP, d = t - c * DP;
    float w = (d < D_SZ) ? wreg[c * D_SZ + d] : 0.0f;
    whi[t] = (_Float16)w;
}

// ---- prep: codebook (±1 fp32) -> f16 (exact), zero-padded to [512][DP] ----
__global__ void prep_cb(const float* __restrict__ cb, _Float16* __restrict__ cbp) {
    int t = blockIdx.x * 256 + threadIdx.x;
    if (t >= KP * DP) return;
    int k = t / DP, d = t - k * DP;
    float v = (k < K_SZ && d < D_SZ) ? cb[k * D_SZ + d] : 0.0f;
    cbp[t] = (_Float16)v;
}

// ---- prep: enc sign mask (0x0000 = +1, 0x8000 = -1).
// Sign-only: sign(sin t) = + iff frac(t/2pi) < 0.5;
//            sign(cos t) = + iff frac(t/2pi) < 0.25 or > 0.75.
// Product > 0 iff predicates agree. fp64-true signs (boundaries measure-zero).
__global__ void prep_enc(const float* __restrict__ x, const float* __restrict__ wp,
                         const float* __restrict__ bp, unsigned short* __restrict__ em) {
    int t = blockIdx.x * 256 + threadIdx.x;
    if (t >= B_SZ * DP) return;
    int b = t / DP, d = t - b * DP;
    unsigned short m = 0;
    if (d < D_SZ) {
        double p = 0.0;
        #pragma unroll
        for (int s = 0; s < S_SZ; ++s)
            p += (double)x[b * S_SZ + s] * (double)wp[d * S_SZ + s];
        const double inv2pi = 0.15915494309189535;
        double t1 = p * inv2pi;
        double f1 = t1 - floor(t1);                     // sin(p) sign
        double t2 = (p + (double)bp[d]) * inv2pi;
        double f2 = t2 - floor(t2);                     // cos(p+b) sign
        bool sin_pos = (f1 < 0.5);
        bool cos_pos = (f2 < 0.25) || (f2 > 0.75);
        m = (sin_pos == cos_pos) ? (unsigned short)0u : (unsigned short)0x8000u;
    }
    em[t] = m;
}

// ---- main: block = 8 batches x 64c x 64k; hi-only f16 MFMA; writes f16 sim tile.
// Each of the 4 waves owns 2 BATCHES x the full 64x64 (c,k) tile.
// Signs XORed onto B fragments (bit-exact: a*(s*b) = s*(a*b)).
// LDS XOR-swizzled: 16-B chunk p of row r holds logical chunk (p ^ (r&7)).
// R5: K-loop unrolled by 2 (buffer index compile-time) -> all 20 ds_reads use
// 6 loop-invariant base VGPRs + constant offset immediates; staging uses
// uniform-base + 32-bit lane offset (saddr form, k0 advance is scalar);
// s_setprio(1) around the MFMA nest. Goal: kill the ~1370 cyc/iter of VALU
// address recomputation that serialized with MFMA (VALUBusy 36% + MfmaUtil 61%).
__global__ __launch_bounds__(256, 2) void gemm_sim(
    const _Float16* __restrict__ whi, const _Float16* __restrict__ cbp,
    const unsigned short* __restrict__ em, _Float16* __restrict__ simh)
{
    const int kt = blockIdx.x >> 1;   // 0..7  k-tile (64 codebook rows)
    const int ct = blockIdx.x & 1;    // 0..1  c-tile (64 classes)
    const int bg = blockIdx.y;        // 0..31 batch group (8 batches)
    const int tid  = threadIdx.x;
    const int wave = tid >> 6;        // owns batches {2*wave, 2*wave+1}
    const int lane = tid & 63;
    const int quad = lane >> 4;
    const int col  = lane & 15;

    __shared__ __align__(16) _Float16 s_whi[2][64 * 64];
    __shared__ __align__(16) _Float16 s_cb [2][64 * 64];
    __shared__ __align__(16) unsigned short s_mask[2][8 * 64];

    f32x4 acc[2][4][4];
    #pragma unroll
    for (int b = 0; b < 2; ++b)
        #pragma unroll
        for (int m = 0; m < 4; ++m)
            #pragma unroll
            for (int n = 0; n < 4; ++n)
                acc[b][m][n] = (f32x4){0.f, 0.f, 0.f, 0.f};

    const int c0  = ct * 64;
    const int kr0 = kt * 64;
    const int bg8 = bg * 8;

    // staging geometry: slot e: row=e>>3, pos p=e&7; global chunk = p^(row&7).
    // 32-bit element offsets (loop-invariant); uniform k0 advances via SGPR base.
    int aoff[2], boff[2], soff[2];
    #pragma unroll
    for (int s = 0; s < 2; ++s) {
        int e = s * 256 + tid;          // 0..511
        int row = e >> 3;
        int p = e & 7;
        int gcol = (p ^ (row & 7)) * 8;
        aoff[s] = (c0 + row) * DP + gcol;
        boff[s] = (kr0 + row) * DP + gcol;
        soff[s] = e * 8;
    }
    const int eoff = (bg8 + (tid >> 3)) * DP + (tid & 7) * 8;

    // fragment-read base pointers (loop-invariant; m/n/b/buf via const offsets)
    const _Float16* pw[2];
    const _Float16* pc[2];
    const unsigned short* pm[2];
    #pragma unroll
    for (int k2 = 0; k2 < 2; ++k2) {
        const int chunk = k2 * 4 + quad;
        const int sw    = (chunk ^ (col & 7)) * 8;
        pw[k2] = &s_whi[0][col * 64 + sw];
        pc[k2] = &s_cb [0][col * 64 + sw];
        pm[k2] = &s_mask[0][wave * 2 * 64 + chunk * 8];
    }

    auto STAGE = [&](int buf, int kb) {
        const int k0 = kb * 64;
        const _Float16* baA = whi + k0;       // uniform + 32-bit lane offset
        const _Float16* baB = cbp + k0;
        const unsigned short* baE = em + k0;
        #pragma unroll
        for (int s = 0; s < 2; ++s) {
            stage16(baA + aoff[s], s_whi[buf] + soff[s]);
            stage16(baB + boff[s], s_cb [buf] + soff[s]);
        }
        if (tid < 64)  // 8 b x 64 ushort masks = 1 KiB; lane-linear LDS dest
            stage16(baE + eoff, s_mask[buf] + tid * 8);
    };

#define COMPUTE(BUF)                                                          \
    {                                                                         \
        u32x4v ah[2][4], br[2][4], mr[2][2];                                  \
        _Pragma("unroll") for (int k2 = 0; k2 < 2; ++k2) {                    \
            _Pragma("unroll") for (int m = 0; m < 4; ++m)                     \
                ah[k2][m] = *(const u32x4v*)(pw[k2] + m * 1024 + (BUF) * 4096); \
            _Pragma("unroll") for (int n = 0; n < 4; ++n)                     \
                br[k2][n] = *(const u32x4v*)(pc[k2] + n * 1024 + (BUF) * 4096); \
            _Pragma("unroll") for (int b = 0; b < 2; ++b)                     \
                mr[k2][b] = *(const u32x4v*)(pm[k2] + b * 64 + (BUF) * 512);  \
        }                                                                     \
        __builtin_amdgcn_s_setprio(1);                                        \
        _Pragma("unroll") for (int k2 = 0; k2 < 2; ++k2) {                    \
            _Pragma("unroll") for (int b = 0; b < 2; ++b) {                   \
                half8 bs[4];                                                  \
                _Pragma("unroll") for (int n = 0; n < 4; ++n)                 \
                    bs[n] = __builtin_bit_cast(half8, br[k2][n] ^ mr[k2][b]); \
                _Pragma("unroll") for (int m = 0; m < 4; ++m) {               \
                    half8 a = __builtin_bit_cast(half8, ah[k2][m]);           \
                    _Pragma("unroll") for (int n = 0; n < 4; ++n)             \
                        acc[b][m][n] = __builtin_amdgcn_mfma_f32_16x16x32_f16( \
                            a, bs[n], acc[b][m][n], 0, 0, 0);                 \
                }                                                             \
            }                                                                 \
        }                                                                     \
        __builtin_amdgcn_s_setprio(0);                                        \
    }

    STAGE(0, 0);
    __syncthreads();   // vmcnt(0) drain: tile 0 resident

    for (int p = 0; p < NIT / 2; ++p) {
        STAGE(1, 2 * p + 1);          // buf1 loads fly under COMPUTE(0)
        COMPUTE(0);
        __syncthreads();              // buf1 landed; buf0 reads done
        if (2 * p + 2 < NIT) STAGE(0, 2 * p + 2);
        COMPUTE(1);
        __syncthreads();              // buf0 landed; buf1 reads done
    }
#undef COMPUTE

    // ---- epilogue: store f16 sim tile. C/D layout (16x16): col=lane&15 (k),
    // row = quad*4 + reg (c). Each wave stores its 2 batches' full 64x64 tile.
    #pragma unroll
    for (int b = 0; b < 2; ++b) {
        const size_t base = ((size_t)(bg8 + wave * 2 + b) * C_SZ + (size_t)c0) * KP;
        #pragma unroll
        for (int m = 0; m < 4; ++m)
            #pragma unroll
            for (int n = 0; n < 4; ++n) {
                const int kg = kr0 + n * 16 + col;
                #pragma unroll
                for (int r = 0; r < 4; ++r) {
                    const int cl = m * 16 + quad * 4 + r;
                    simh[base + (size_t)cl * KP + kg] = (_Float16)acc[b][m][n][r];
                }
            }
    }
}

// ---- pass 2: per (b,c) row of 512 f16 sims: top-2 over k<500; gap >= THR is
// provably safe (2 x 0.29 error bound < 1.0); else flag row for exact repair.
__global__ __launch_bounds__(256) void argmax_gap(
    const _Float16* __restrict__ simh, float* __restrict__ out,
    int* __restrict__ counter, int* __restrict__ list)
{
    const int wave = threadIdx.x >> 6, lane = threadIdx.x & 63;
    const int row = blockIdx.x * 4 + wave;       // 8192 blocks x 4 rows
    const half8 v = *(const half8*)(simh + (size_t)row * KP + lane * 8);
    float bv = -3.0e38f, bv2 = -3.0e38f; int bk = 0x7fffffff;
    #pragma unroll
    for (int j = 0; j < 8; ++j) {
        const int k = lane * 8 + j;
        const float f = (k < K_SZ) ? (float)v[j] : -3.0e38f;
        if (f > bv)       { bv2 = bv; bv = f; bk = k; }
        else if (f > bv2) { bv2 = f; }
    }
    #pragma unroll
    for (int off = 1; off < 64; off <<= 1) {
        const float ov  = __shfl_xor(bv,  off, 64);
        const int   ok  = __shfl_xor(bk,  off, 64);
        const float ov2 = __shfl_xor(bv2, off, 64);
        if (ov > bv || (ov == bv && ok < bk)) { bv2 = fmaxf(bv, ov2); bv = ov; bk = ok; }
        else                                  { bv2 = fmaxf(ov, bv2); }
    }
    if (lane == 0) {
        out[row] = (float)bk * (61.5f / 499.0f) - 19.9f;
        if (bv - bv2 < THR) {
            const int idx = atomicAdd(counter, 1);
            if (idx < RCAP) list[idx] = row;
        }
    }
}

// ---- pass 3 (R5 rewrite): wave per flagged row; candidate set via ballot.
// Exact dot now THROUGHPUT-bound: float4/ushort4 vector loads (40 chunks vs
// 157 scalar iters), 4 independent fp64 accumulators (breaks the dependent
// chain that was ~250 cyc/iter latency-exposed), sign applied by fp32 bit-XOR
// (exact: codebook is ±1, em is a sign mask). Grid 1024 blocks = 4096 waves
// -> ~1 row/wave.
__global__ __launch_bounds__(256) void repair(
    const _Float16* __restrict__ simh, const int* __restrict__ list,
    const int* __restrict__ counter, const unsigned short* __restrict__ em,
    const float* __restrict__ wreg, const _Float16* __restrict__ cbp,
    float* __restrict__ out)
{
    const int wave = threadIdx.x >> 6, lane = threadIdx.x & 63;
    const int wid = blockIdx.x * 4 + wave;
    const int nw  = gridDim.x * 4;
    int n = *counter;
    if (n > RCAP) n = RCAP;
    for (int i = wid; i < n; i += nw) {
        const int row = list[i];
        const int b = row >> 7, c = row & 127;
        const half8 v = *(const half8*)(simh + (size_t)row * KP + lane * 8);
        float vf[8];
        float mx = -3.0e38f;
        #pragma unroll
        for (int j = 0; j < 8; ++j) {
            const int k = lane * 8 + j;
            vf[j] = (k < K_SZ) ? (float)v[j] : -3.0e38f;
            mx = fmaxf(mx, vf[j]);
        }
        #pragma unroll
        for (int off = 1; off < 64; off <<= 1)
            mx = fmaxf(mx, __shfl_xor(mx, off, 64));
        const float thr = mx - THR;   // true argmax provably within THR of stored max

        const float* wr = wreg + (size_t)c * D_SZ;
        const unsigned short* eb = em + (size_t)b * DP;

        double best = -1.0e300; int bestk = 0x7fffffff;
        #pragma unroll
        for (int j = 0; j < 8; ++j) {
            unsigned long long bal = __ballot(vf[j] >= thr);
            while (bal) {
                const int l = __ffsll((long long)bal) - 1;
                bal &= bal - 1;
                const int k = l * 8 + j;          // candidate codebook row
                const unsigned short* ck = (const unsigned short*)(cbp + (size_t)k * DP);
                double s0 = 0.0, s1 = 0.0, s2 = 0.0, s3 = 0.0;
                // D_SZ % 4 == 0, so d<D_SZ with d%4==0 implies full float4 in-bounds
                for (int d = lane * 4; d < D_SZ; d += 256) {
                    const f32x4 w  = *(const f32x4*)(wr + d);
                    const u16x4 e4 = *(const u16x4*)(eb + d);
                    const u16x4 c4 = *(const u16x4*)(ck + d);
                    const u32x4b wb = __builtin_bit_cast(u32x4b, w);
                    u32x4b sb;
                    #pragma unroll
                    for (int q = 0; q < 4; ++q)
                        sb[q] = wb[q] ^ ((unsigned int)((e4[q] ^ c4[q]) & 0x8000u) << 16);
                    const f32x4 ws = __builtin_bit_cast(f32x4, sb);
                    s0 += (double)ws[0];
                    s1 += (double)ws[1];
                    s2 += (double)ws[2];
                    s3 += (double)ws[3];
                }
                double s = (s0 + s1) + (s2 + s3);
                #pragma unroll
                for (int off = 1; off < 64; off <<= 1)
                    s += __shfl_xor(s, off, 64);
                if (s > best || (s == best && k < bestk)) { best = s; bestk = k; }
            }
        }
        if (lane == 0)
            out[row] = (float)bestk * (61.5f / 499.0f) - 19.9f;
    }
}

extern "C" void kernel_launch(void* const* d_in, const int* in_sizes, int n_in,
                              void* d_out, int out_size, void* d_ws, size_t ws_size,
                              hipStream_t stream) {
    const float* x    = (const float*)d_in[0];
    const float* wp   = (const float*)d_in[1];
    const float* bp   = (const float*)d_in[2];
    const float* wreg = (const float*)d_in[3];
    const float* cb   = (const float*)d_in[4];
    float* out = (float*)d_out;

    char* ws = (char*)d_ws;
    size_t o = 0;
    auto take = [&](size_t bytes) -> char* {
        o = (o + 255) & ~(size_t)255;
        char* p = ws + o;
        o += bytes;
        return p;
    };
    _Float16* whi       = (_Float16*)take(sizeof(_Float16) * C_SZ * DP);
    _Float16* cbp       = (_Float16*)take(sizeof(_Float16) * KP * DP);
    unsigned short* em  = (unsigned short*)take(sizeof(unsigned short) * B_SZ * DP);
    _Float16* simh      = (_Float16*)take(sizeof(_Float16) * (size_t)B_SZ * C_SZ * KP);
    int* counter        = (int*)take(sizeof(int));
    int* list           = (int*)take(sizeof(int) * RCAP);
    (void)ws_size; (void)in_sizes; (void)n_in; (void)out_size;

    prep_whi<<<(C_SZ * DP + 255) / 256, 256, 0, stream>>>(wreg, whi, counter);
    prep_cb<<<(KP * DP + 255) / 256, 256, 0, stream>>>(cb, cbp);
    prep_enc<<<(B_SZ * DP + 255) / 256, 256, 0, stream>>>(x, wp, bp, em);

    dim3 g(16, 32);  // x: kt*2+ct, y: batch group of 8 -> 512 blocks = 2/CU exactly
    gemm_sim<<<g, 256, 0, stream>>>(whi, cbp, em, simh);

    // 8192 blocks x 4 rows = 32768 (b,c) rows
    argmax_gap<<<(B_SZ * C_SZ) / 4, 256, 0, stream>>>(simh, out, counter, list);
    repair<<<1024, 256, 0, stream>>>(simh, list, counter, em, wreg, cbp, out);
}

// Round 6
// 366.182 us; speedup vs baseline: 1.5506x; 1.1305x over previous
//
#include <hip/hip_runtime.h>
#include <math.h>

// Problem constants
#define B_SZ 256
#define S_SZ 6
#define D_SZ 10000
#define DP   10112      // D padded to 158*64
#define C_SZ 128
#define K_SZ 500
#define KP   512        // codebook rows padded (8 k-tiles of 64)
#define NIT  (DP / 64)  // 158 K-iterations
#define THR  1.0f       // repair window; hi-only error bound <= ~0.29/value, 0.58/gap
#define RCAP 32768      // repair list capacity = all rows (never overflows)

typedef _Float16       half8 __attribute__((ext_vector_type(8)));
typedef float          f32x4 __attribute__((ext_vector_type(4)));
typedef unsigned int   u32x4v __attribute__((ext_vector_type(4)));
typedef unsigned short u16x4 __attribute__((ext_vector_type(4)));
typedef unsigned int   u32x4b __attribute__((ext_vector_type(4)));

__device__ __forceinline__ void stage16(const void* g, void* l) {
    __builtin_amdgcn_global_load_lds(
        (const __attribute__((address_space(1))) unsigned int*)g,
        (__attribute__((address_space(3))) unsigned int*)l, 16, 0, 0);
}

// ---- fused prep (R6): one BW-bound kernel does all three conversions.
// t in [0, KP*DP): codebook ±1 fp32 -> f16 zero-padded.
// t in [0, C_SZ*DP): W_reg fp32 -> f16 hi (near-ties repaired exactly later).
// t in [0, B_SZ*DP): enc sign mask (0x0000=+1, 0x8000=-1), sign-only sincos:
//   sign(sin t) = + iff frac(t/2pi) < 0.5
//   sign(cos t) = + iff frac(t/2pi) < 0.25 or > 0.75
// product > 0 iff predicates agree; fp64-true signs (boundaries measure-zero).
__global__ void prep_fused(const float* __restrict__ cb, _Float16* __restrict__ cbp,
                           const float* __restrict__ wreg, _Float16* __restrict__ whi,
                           const float* __restrict__ x, const float* __restrict__ wp,
                           const float* __restrict__ bp, unsigned short* __restrict__ em,
                           int* __restrict__ counter) {
    if (blockIdx.x == 0 && threadIdx.x == 0) *counter = 0;  // zero repair counter early
    int t = blockIdx.x * 256 + threadIdx.x;
    if (t < KP * DP) {
        int k = t / DP, d = t - k * DP;
        float v = (k < K_SZ && d < D_SZ) ? cb[k * D_SZ + d] : 0.0f;
        cbp[t] = (_Float16)v;
    }
    if (t < C_SZ * DP) {
        int c = t / DP, d = t - c * DP;
        float w = (d < D_SZ) ? wreg[c * D_SZ + d] : 0.0f;
        whi[t] = (_Float16)w;
    }
    if (t < B_SZ * DP) {
        int b = t / DP, d = t - b * DP;
        unsigned short m = 0;
        if (d < D_SZ) {
            double p = 0.0;
            #pragma unroll
            for (int s = 0; s < S_SZ; ++s)
                p += (double)x[b * S_SZ + s] * (double)wp[d * S_SZ + s];
            const double inv2pi = 0.15915494309189535;
            double t1 = p * inv2pi;
            double f1 = t1 - floor(t1);                     // sin(p) sign
            double t2 = (p + (double)bp[d]) * inv2pi;
            double f2 = t2 - floor(t2);                     // cos(p+b) sign
            bool sin_pos = (f1 < 0.5);
            bool cos_pos = (f2 < 0.25) || (f2 > 0.75);
            m = (sin_pos == cos_pos) ? (unsigned short)0u : (unsigned short)0x8000u;
        }
        em[t] = m;
    }
}

// ---- main: block = 8 batches x 64c x 64k; hi-only f16 MFMA; writes f16 sim tile.
// Each of the 4 waves owns 2 BATCHES x the full 64x64 (c,k) tile.
// Signs XORed onto B fragments (bit-exact: a*(s*b) = s*(a*b)).
// LDS XOR-swizzled: 16-B chunk p of row r holds logical chunk (p ^ (r&7)).
// Double-buffered staging: tile t+1's global_load_lds issued BEFORE tile t's
// MFMAs; the vmcnt(0) drain at the end-of-iter barrier finds loads landed.
// [R6: exact revert to the R4 version — R5's unroll-2/setprio/static-pointer
//  variant raised live VGPRs past the 128 allocation step and spilled
//  (+15 MB scratch traffic/dispatch, MfmaUtil 61->51, +37 us).]
__global__ __launch_bounds__(256, 2) void gemm_sim(
    const _Float16* __restrict__ whi, const _Float16* __restrict__ cbp,
    const unsigned short* __restrict__ em, _Float16* __restrict__ simh)
{
    const int kt = blockIdx.x >> 1;   // 0..7  k-tile (64 codebook rows)
    const int ct = blockIdx.x & 1;    // 0..1  c-tile (64 classes)
    const int bg = blockIdx.y;        // 0..31 batch group (8 batches)
    const int tid  = threadIdx.x;
    const int wave = tid >> 6;        // owns batches {2*wave, 2*wave+1}
    const int lane = tid & 63;
    const int quad = lane >> 4;
    const int col  = lane & 15;

    __shared__ __align__(16) _Float16 s_whi[2][64 * 64];
    __shared__ __align__(16) _Float16 s_cb [2][64 * 64];
    __shared__ __align__(16) unsigned short s_mask[2][8 * 64];

    f32x4 acc[2][4][4];
    #pragma unroll
    for (int b = 0; b < 2; ++b)
        #pragma unroll
        for (int m = 0; m < 4; ++m)
            #pragma unroll
            for (int n = 0; n < 4; ++n)
                acc[b][m][n] = (f32x4){0.f, 0.f, 0.f, 0.f};

    const int c0  = ct * 64;
    const int kr0 = kt * 64;
    const int bg8 = bg * 8;

    // staging geometry: slot e: row=e>>3, pos p=e&7; global chunk = p^(row&7)
    size_t abase[2], bbase[2];
    int soff[2];
    #pragma unroll
    for (int s = 0; s < 2; ++s) {
        int e = s * 256 + tid;          // 0..511
        int row = e >> 3;
        int p = e & 7;
        int gcol = (p ^ (row & 7)) * 8;
        abase[s] = (size_t)(c0 + row) * DP + gcol;
        bbase[s] = (size_t)(kr0 + row) * DP + gcol;
        soff[s] = e * 8;
    }
    const size_t embase = (size_t)(bg8 + (tid >> 3)) * DP + (tid & 7) * 8;

    auto STAGE = [&](int buf, int kb) {
        const int k0 = kb * 64;
        #pragma unroll
        for (int s = 0; s < 2; ++s) {
            stage16(whi + abase[s] + k0, &s_whi[buf][soff[s]]);
            stage16(cbp + bbase[s] + k0, &s_cb [buf][soff[s]]);
        }
        if (tid < 64)  // 8 b x 64 ushort masks = 1 KiB; lane-linear LDS dest
            stage16(em + embase + k0, &s_mask[buf][tid * 8]);
    };

    STAGE(0, 0);
    __syncthreads();   // compiler emits vmcnt(0) drain: tile 0 resident
    int cur = 0;

    for (int kb = 0; kb < NIT; ++kb) {
        if (kb + 1 < NIT) STAGE(cur ^ 1, kb + 1);   // next tile in flight under MFMAs

        // preload both k2 phases' fragments: later loads stay in flight
        // (lgkmcnt>0) while earlier MFMAs run.
        u32x4v ah[2][4], br[2][4], mr[2][2];
        #pragma unroll
        for (int k2 = 0; k2 < 2; ++k2) {
            const int chunk = k2 * 4 + quad;
            const int sw    = (chunk ^ (col & 7)) * 8;
            #pragma unroll
            for (int m = 0; m < 4; ++m)
                ah[k2][m] = *(const u32x4v*)(&s_whi[cur][(m * 16 + col) * 64 + sw]);
            #pragma unroll
            for (int n = 0; n < 4; ++n)
                br[k2][n] = *(const u32x4v*)(&s_cb[cur][(n * 16 + col) * 64 + sw]);
            #pragma unroll
            for (int b = 0; b < 2; ++b)
                mr[k2][b] = *(const u32x4v*)(&s_mask[cur][(wave * 2 + b) * 64 + chunk * 8]);
        }
        #pragma unroll
        for (int k2 = 0; k2 < 2; ++k2) {
            #pragma unroll
            for (int b = 0; b < 2; ++b) {
                half8 bs[4];
                #pragma unroll
                for (int n = 0; n < 4; ++n)
                    bs[n] = __builtin_bit_cast(half8, br[k2][n] ^ mr[k2][b]);
                #pragma unroll
                for (int m = 0; m < 4; ++m) {
                    half8 a = __builtin_bit_cast(half8, ah[k2][m]);
                    #pragma unroll
                    for (int n = 0; n < 4; ++n)
                        acc[b][m][n] = __builtin_amdgcn_mfma_f32_16x16x32_f16(a, bs[n], acc[b][m][n], 0, 0, 0);
                }
            }
        }
        __syncthreads();   // vmcnt(0)+lgkmcnt(0) drain: next tile ready, reads done
        cur ^= 1;
    }

    // ---- epilogue: store f16 sim tile. C/D layout (16x16): col=lane&15 (k),
    // row = quad*4 + reg (c). Each wave stores its 2 batches' full 64x64 tile.
    #pragma unroll
    for (int b = 0; b < 2; ++b) {
        const size_t base = ((size_t)(bg8 + wave * 2 + b) * C_SZ + (size_t)c0) * KP;
        #pragma unroll
        for (int m = 0; m < 4; ++m)
            #pragma unroll
            for (int n = 0; n < 4; ++n) {
                const int kg = kr0 + n * 16 + col;
                #pragma unroll
                for (int r = 0; r < 4; ++r) {
                    const int cl = m * 16 + quad * 4 + r;
                    simh[base + (size_t)cl * KP + kg] = (_Float16)acc[b][m][n][r];
                }
            }
    }
}

// ---- pass 2: per (b,c) row of 512 f16 sims: top-2 over k<500; gap >= THR is
// provably safe (2 x 0.29 error bound < 1.0); else flag row for exact repair.
__global__ __launch_bounds__(256) void argmax_gap(
    const _Float16* __restrict__ simh, float* __restrict__ out,
    int* __restrict__ counter, int* __restrict__ list)
{
    const int wave = threadIdx.x >> 6, lane = threadIdx.x & 63;
    const int row = blockIdx.x * 4 + wave;       // 8192 blocks x 4 rows
    const half8 v = *(const half8*)(simh + (size_t)row * KP + lane * 8);
    float bv = -3.0e38f, bv2 = -3.0e38f; int bk = 0x7fffffff;
    #pragma unroll
    for (int j = 0; j < 8; ++j) {
        const int k = lane * 8 + j;
        const float f = (k < K_SZ) ? (float)v[j] : -3.0e38f;
        if (f > bv)       { bv2 = bv; bv = f; bk = k; }
        else if (f > bv2) { bv2 = f; }
    }
    #pragma unroll
    for (int off = 1; off < 64; off <<= 1) {
        const float ov  = __shfl_xor(bv,  off, 64);
        const int   ok  = __shfl_xor(bk,  off, 64);
        const float ov2 = __shfl_xor(bv2, off, 64);
        if (ov > bv || (ov == bv && ok < bk)) { bv2 = fmaxf(bv, ov2); bv = ov; bk = ok; }
        else                                  { bv2 = fmaxf(ov, bv2); }
    }
    if (lane == 0) {
        out[row] = (float)bk * (61.5f / 499.0f) - 19.9f;
        if (bv - bv2 < THR) {
            const int idx = atomicAdd(counter, 1);
            if (idx < RCAP) list[idx] = row;
        }
    }
}

// ---- pass 3: wave per flagged row; candidate set via ballot (~2-3/row).
// Exact dot is throughput-bound: float4/ushort4 vector loads, 4 independent
// fp64 accumulators, sign applied by fp32 bit-XOR (exact: codebook is ±1,
// em is a sign mask). Grid 1024 blocks = 4096 waves -> ~1 row/wave.
__global__ __launch_bounds__(256) void repair(
    const _Float16* __restrict__ simh, const int* __restrict__ list,
    const int* __restrict__ counter, const unsigned short* __restrict__ em,
    const float* __restrict__ wreg, const _Float16* __restrict__ cbp,
    float* __restrict__ out)
{
    const int wave = threadIdx.x >> 6, lane = threadIdx.x & 63;
    const int wid = blockIdx.x * 4 + wave;
    const int nw  = gridDim.x * 4;
    int n = *counter;
    if (n > RCAP) n = RCAP;
    for (int i = wid; i < n; i += nw) {
        const int row = list[i];
        const int b = row >> 7, c = row & 127;
        const half8 v = *(const half8*)(simh + (size_t)row * KP + lane * 8);
        float vf[8];
        float mx = -3.0e38f;
        #pragma unroll
        for (int j = 0; j < 8; ++j) {
            const int k = lane * 8 + j;
            vf[j] = (k < K_SZ) ? (float)v[j] : -3.0e38f;
            mx = fmaxf(mx, vf[j]);
        }
        #pragma unroll
        for (int off = 1; off < 64; off <<= 1)
            mx = fmaxf(mx, __shfl_xor(mx, off, 64));
        const float thr = mx - THR;   // true argmax provably within THR of stored max

        const float* wr = wreg + (size_t)c * D_SZ;
        const unsigned short* eb = em + (size_t)b * DP;

        double best = -1.0e300; int bestk = 0x7fffffff;
        #pragma unroll
        for (int j = 0; j < 8; ++j) {
            unsigned long long bal = __ballot(vf[j] >= thr);
            while (bal) {
                const int l = __ffsll((long long)bal) - 1;
                bal &= bal - 1;
                const int k = l * 8 + j;          // candidate codebook row
                const unsigned short* ck = (const unsigned short*)(cbp + (size_t)k * DP);
                double s0 = 0.0, s1 = 0.0, s2 = 0.0, s3 = 0.0;
                // D_SZ % 4 == 0, so d<D_SZ with d%4==0 implies full float4 in-bounds
                for (int d = lane * 4; d < D_SZ; d += 256) {
                    const f32x4 w  = *(const f32x4*)(wr + d);
                    const u16x4 e4 = *(const u16x4*)(eb + d);
                    const u16x4 c4 = *(const u16x4*)(ck + d);
                    const u32x4b wb = __builtin_bit_cast(u32x4b, w);
                    u32x4b sb;
                    #pragma unroll
                    for (int q = 0; q < 4; ++q)
                        sb[q] = wb[q] ^ ((unsigned int)((e4[q] ^ c4[q]) & 0x8000u) << 16);
                    const f32x4 ws = __builtin_bit_cast(f32x4, sb);
                    s0 += (double)ws[0];
                    s1 += (double)ws[1];
                    s2 += (double)ws[2];
                    s3 += (double)ws[3];
                }
                double s = (s0 + s1) + (s2 + s3);
                #pragma unroll
                for (int off = 1; off < 64; off <<= 1)
                    s += __shfl_xor(s, off, 64);
                if (s > best || (s == best && k < bestk)) { best = s; bestk = k; }
            }
        }
        if (lane == 0)
            out[row] = (float)bestk * (61.5f / 499.0f) - 19.9f;
    }
}

extern "C" void kernel_launch(void* const* d_in, const int* in_sizes, int n_in,
                              void* d_out, int out_size, void* d_ws, size_t ws_size,
                              hipStream_t stream) {
    const float* x    = (const float*)d_in[0];
    const float* wp   = (const float*)d_in[1];
    const float* bp   = (const float*)d_in[2];
    const float* wreg = (const float*)d_in[3];
    const float* cb   = (const float*)d_in[4];
    float* out = (float*)d_out;

    char* ws = (char*)d_ws;
    size_t o = 0;
    auto take = [&](size_t bytes) -> char* {
        o = (o + 255) & ~(size_t)255;
        char* p = ws + o;
        o += bytes;
        return p;
    };
    _Float16* whi       = (_Float16*)take(sizeof(_Float16) * C_SZ * DP);
    _Float16* cbp       = (_Float16*)take(sizeof(_Float16) * KP * DP);
    unsigned short* em  = (unsigned short*)take(sizeof(unsigned short) * B_SZ * DP);
    _Float16* simh      = (_Float16*)take(sizeof(_Float16) * (size_t)B_SZ * C_SZ * KP);
    int* counter        = (int*)take(sizeof(int));
    int* list           = (int*)take(sizeof(int) * RCAP);
    (void)ws_size; (void)in_sizes; (void)n_in; (void)out_size;

    prep_fused<<<(KP * DP + 255) / 256, 256, 0, stream>>>(
        cb, cbp, wreg, whi, x, wp, bp, em, counter);

    dim3 g(16, 32);  // x: kt*2+ct, y: batch group of 8 -> 512 blocks = 2/CU exactly
    gemm_sim<<<g, 256, 0, stream>>>(whi, cbp, em, simh);

    // 8192 blocks x 4 rows = 32768 (b,c) rows
    argmax_gap<<<(B_SZ * C_SZ) / 4, 256, 0, stream>>>(simh, out, counter, list);
    repair<<<1024, 256, 0, stream>>>(simh, list, counter, em, wreg, cbp, out);
}